// Round 7
// baseline (147.182 us; speedup 1.0000x reference)
//
#include <hip/hip_runtime.h>
#include <hip/hip_bf16.h>
#include <math.h>

// y[b,l,d] = x[b,l,d] * softplus((x@W1+b1)[b,l,d]) * sum_n((x@W2+b2)*(x@W3+b3))[b,l,n]

#define GLB(p) ((const __attribute__((address_space(1))) void*)(p))
#define LDSP(p) ((__attribute__((address_space(3))) void*)(p))

namespace {

constexpr int Dd   = 1024;
constexpr int ROWS = 8192;

typedef __bf16 bf16x8 __attribute__((ext_vector_type(8)));
typedef float  floatx4 __attribute__((ext_vector_type(4)));

__device__ __forceinline__ float softplus_fast(float v) {
    float l = __logf(1.0f + __expf(v));
    return v > 15.0f ? v : l;
}
__device__ __forceinline__ float bf_lo(unsigned short u) {
    union { unsigned q; float f; } c; c.q = ((unsigned)u) << 16; return c.f;
}

// ---------------------------------------------------------------------------
// w23: grid 16 — W2,W3 [k][16] fp32 -> W2t,W3t [16][k] bf16.
// ---------------------------------------------------------------------------
__global__ __launch_bounds__(256) void w23_kernel(
    const float* __restrict__ W2, const float* __restrict__ W3,
    __bf16* __restrict__ W2t, __bf16* __restrict__ W3t)
{
    const int t  = threadIdx.x;
    const int n  = t >> 4;
    const int k0 = blockIdx.x * 64 + (t & 15) * 4;
    ushort4 a, b;
    union { __bf16 h; unsigned short u; } c;
    c.h = (__bf16)W2[(size_t)(k0 + 0) * 16 + n]; a.x = c.u;
    c.h = (__bf16)W2[(size_t)(k0 + 1) * 16 + n]; a.y = c.u;
    c.h = (__bf16)W2[(size_t)(k0 + 2) * 16 + n]; a.z = c.u;
    c.h = (__bf16)W2[(size_t)(k0 + 3) * 16 + n]; a.w = c.u;
    c.h = (__bf16)W3[(size_t)(k0 + 0) * 16 + n]; b.x = c.u;
    c.h = (__bf16)W3[(size_t)(k0 + 1) * 16 + n]; b.y = c.u;
    c.h = (__bf16)W3[(size_t)(k0 + 2) * 16 + n]; b.z = c.u;
    c.h = (__bf16)W3[(size_t)(k0 + 3) * 16 + n]; b.w = c.u;
    *(ushort4*)&W2t[(size_t)n * Dd + k0] = a;
    *(ushort4*)&W3t[(size_t)n * Dd + k0] = b;
}

// ---------------------------------------------------------------------------
// prep: blocks 0..511 — 16 rows each: x fp32 -> bf16 Xb (A-frag layout) and
//       s[row] via MFMA vs W2t/W3t b128 frags. 4 waves K-split 256.
//       blocks 512..767 — W1 [k][n] fp32 -> W1t [n][k] bf16 (64x64 tiles).
// ---------------------------------------------------------------------------
__global__ __launch_bounds__(256, 4) void prep_kernel(
    const float* __restrict__ X, const float* __restrict__ W1,
    const __bf16* __restrict__ W2t, const float* __restrict__ b2,
    const __bf16* __restrict__ W3t, const float* __restrict__ b3,
    __bf16* __restrict__ Xb, __bf16* __restrict__ W1t, float* __restrict__ Sv)
{
    const int t = threadIdx.x;

    if (blockIdx.x >= 512) {
        __shared__ __bf16 tile[64][66];
        const int bidx = blockIdx.x - 512;
        const int bi = bidx >> 4, bj = bidx & 15;
        const int c = t & 63, r4 = t >> 6;
        #pragma unroll
        for (int i = 0; i < 16; ++i) {
            const int r = i * 4 + r4;
            tile[r][c] = (__bf16)W1[(size_t)(bi * 64 + r) * Dd + bj * 64 + c];
        }
        __syncthreads();
        #pragma unroll
        for (int i = 0; i < 16; ++i) {
            const int r = i * 4 + r4;
            W1t[(size_t)(bj * 64 + r) * Dd + bi * 64 + c] = tile[c][r];
        }
        return;
    }

    __shared__ float red[4][2][16][16];   // [wave][B/C][row][n]
    const int w = t >> 6, lane = t & 63;
    const int l15 = lane & 15, quad = lane >> 4;
    const int row0 = blockIdx.x * 16;
    const int kw = w * 256;
    const size_t xoff = (size_t)(row0 + l15) * Dd;
    const size_t woff = (size_t)l15 * Dd;

    floatx4 acc0 = {0.f, 0.f, 0.f, 0.f}, acc1 = {0.f, 0.f, 0.f, 0.f};
    #pragma unroll
    for (int ks = 0; ks < 8; ++ks) {
        const int k0 = kw + ks * 32 + quad * 8;
        const float4 xa = *(const float4*)&X[xoff + k0];
        const float4 xb = *(const float4*)&X[xoff + k0 + 4];
        bf16x8 af;
        af[0] = (__bf16)xa.x; af[1] = (__bf16)xa.y;
        af[2] = (__bf16)xa.z; af[3] = (__bf16)xa.w;
        af[4] = (__bf16)xb.x; af[5] = (__bf16)xb.y;
        af[6] = (__bf16)xb.z; af[7] = (__bf16)xb.w;
        *(bf16x8*)&Xb[xoff + k0] = af;
        const bf16x8 w2f = *(const bf16x8*)&W2t[woff + k0];
        const bf16x8 w3f = *(const bf16x8*)&W3t[woff + k0];
        acc0 = __builtin_amdgcn_mfma_f32_16x16x32_bf16(af, w2f, acc0, 0, 0, 0);
        acc1 = __builtin_amdgcn_mfma_f32_16x16x32_bf16(af, w3f, acc1, 0, 0, 0);
    }
    #pragma unroll
    for (int r = 0; r < 4; ++r) {
        red[w][0][quad * 4 + r][l15] = acc0[r];
        red[w][1][quad * 4 + r][l15] = acc1[r];
    }
    __syncthreads();
    {
        const int r = t >> 4, n = t & 15;
        float B = b2[n], C = b3[n];
        #pragma unroll
        for (int ww = 0; ww < 4; ++ww) {
            B += red[ww][0][r][n];
            C += red[ww][1][r][n];
        }
        float p = B * C;
        p += __shfl_xor(p, 1); p += __shfl_xor(p, 2);
        p += __shfl_xor(p, 4); p += __shfl_xor(p, 8);
        if (n == 0) Sv[row0 + r] = p;
    }
}

// ---------------------------------------------------------------------------
// gemm: 128x128 tile, BK=32, 3-deep global_load_lds pipeline. One fused
// `s_waitcnt vmcnt(4) lgkmcnt(0); s_barrier` per K-step drains only the tile
// issued 2 iters ago; the next tile's DMA stays in flight across the barrier
// (AITER pattern). FINAL iteration must wait vmcnt(0): only 4 instrs remain
// outstanding there, so vmcnt(4) would be a no-op and compute could read
// un-landed LDS (R6 bug, absmax 2.875). Prefetch t+2 goes to the buffer last
// read at iter t-1 (safe: all readers passed a barrier since; lgkmcnt(0)
// closes the in-flight ds_read hazard). XOR-slot swizzle, fused epilogue.
// ---------------------------------------------------------------------------
__global__ __launch_bounds__(256, 2) void gemm_kernel(
    const __bf16* __restrict__ Xb, const __bf16* __restrict__ W1t,
    const float* __restrict__ Sv, const float* __restrict__ b1,
    float* __restrict__ Y)
{
    // 3 tile buffers x (A 4096 + B 4096 bf16) = 48 KB
    __shared__ __attribute__((aligned(16))) __bf16 lds[3 * 8192];
    const int t = threadIdx.x, lane = t & 63;
    const int w = t >> 6, wm = w & 1, wn = w >> 1;
    const int l15 = lane & 15, quad = lane >> 4;
    const int cb = blockIdx.x & 7, rb = blockIdx.x >> 3;  // cb ~ XCD id
    const int row0 = rb * 128, col0 = cb * 128;

    floatx4 acc[4][4] = {};

    // R2-verified staging map: slot u -> (rowL, chunk) with c4 = (u&7)^((u>>3)&7)
    const __bf16* gA[2]; const __bf16* gB[2];
    int dA[2], dB[2];
    #pragma unroll
    for (int r = 0; r < 2; ++r) {
        const int u = r * 256 + t;
        const int p = u >> 3, s = u & 7, c4 = s ^ (p & 7);
        const int rowL = 2 * p + (c4 >> 2), chk = c4 & 3;
        gA[r] = Xb  + (size_t)(row0 + rowL) * Dd + chk * 8;
        gB[r] = W1t + (size_t)(col0 + rowL) * Dd + chk * 8;
        dA[r] = u * 8;
        dB[r] = 4096 + u * 8;
    }

    auto issue = [&](int tt, int c) {   // 4 glds instrs per wave per tile
        const int base = c * 8192;
        #pragma unroll
        for (int r = 0; r < 2; ++r) {
            __builtin_amdgcn_global_load_lds(GLB(gA[r] + tt * 32),
                                             LDSP(&lds[base + dA[r]]), 16, 0, 0);
            __builtin_amdgcn_global_load_lds(GLB(gB[r] + tt * 32),
                                             LDSP(&lds[base + dB[r]]), 16, 0, 0);
        }
    };
    auto compute = [&](int c) {
        const int base = c * 8192;
        bf16x8 af[4], bfr[4];
        #pragma unroll
        for (int mt = 0; mt < 4; ++mt) {
            const int rl = wm * 64 + mt * 16 + l15;
            const int p = rl >> 1, c4 = ((rl & 1) << 2) | quad, s = c4 ^ (p & 7);
            af[mt] = *(const bf16x8*)&lds[base + p * 64 + s * 8];
        }
        #pragma unroll
        for (int nt = 0; nt < 4; ++nt) {
            const int nl = wn * 64 + nt * 16 + l15;
            const int p = nl >> 1, c4 = ((nl & 1) << 2) | quad, s = c4 ^ (p & 7);
            bfr[nt] = *(const bf16x8*)&lds[base + 4096 + p * 64 + s * 8];
        }
        #pragma unroll
        for (int mt = 0; mt < 4; ++mt)
            #pragma unroll
            for (int nt = 0; nt < 4; ++nt)
                acc[mt][nt] = __builtin_amdgcn_mfma_f32_16x16x32_bf16(
                    af[mt], bfr[nt], acc[mt][nt], 0, 0, 0);
    };

    issue(0, 0);
    issue(1, 1);
    #pragma unroll
    for (int tt = 0; tt < 32; ++tt) {
        if (tt == 31) {
            // tail: only batch 31 (4 instrs) outstanding -> must drain fully
            asm volatile("s_waitcnt vmcnt(0) lgkmcnt(0)\n\ts_barrier" ::: "memory");
        } else {
            // steady state: 8 outstanding; drain the 4 oldest (batch tt)
            asm volatile("s_waitcnt vmcnt(4) lgkmcnt(0)\n\ts_barrier" ::: "memory");
        }
        if (tt + 2 < 32) issue(tt + 2, (tt + 2) % 3);
        compute(tt % 3);
    }

    // epilogue: C/D layout col = l15, row = quad*4 + rr
    float bias[4];
    #pragma unroll
    for (int nt = 0; nt < 4; ++nt) bias[nt] = b1[col0 + wn * 64 + nt * 16 + l15];

    #pragma unroll
    for (int mt = 0; mt < 4; ++mt) {
        #pragma unroll
        for (int rr = 0; rr < 4; ++rr) {
            const int row = row0 + wm * 64 + mt * 16 + quad * 4 + rr;
            const float sv = Sv[row];
            const unsigned short* xrow =
                (const unsigned short*)(Xb + (size_t)row * Dd + col0);
            float* yrow = Y + (size_t)row * Dd + col0;
            #pragma unroll
            for (int nt = 0; nt < 4; ++nt) {
                const int cl = wn * 64 + nt * 16 + l15;
                const float v  = acc[mt][nt][rr] + bias[nt];
                const float sp = softplus_fast(v);
                yrow[cl] = bf_lo(xrow[cl]) * sp * sv;
            }
        }
    }
}

} // namespace

extern "C" void kernel_launch(void* const* d_in, const int* in_sizes, int n_in,
                              void* d_out, int out_size, void* d_ws, size_t ws_size,
                              hipStream_t stream)
{
    const float* X  = (const float*)d_in[0];
    const float* W1 = (const float*)d_in[1];
    const float* b1 = (const float*)d_in[2];
    const float* W2 = (const float*)d_in[3];
    const float* b2 = (const float*)d_in[4];
    const float* W3 = (const float*)d_in[5];
    const float* b3 = (const float*)d_in[6];
    // d_in[7] = A is dead code in the reference.
    float* Y = (float*)d_out;

    // workspace: Xb 16MB | W1t 2MB | Sv 32KB | W2t 32KB | W3t 32KB
    char* ws = (char*)d_ws;
    __bf16* Xb  = (__bf16*)ws;
    __bf16* W1t = (__bf16*)(ws + 16777216);
    float*  Sv  = (float*) (ws + 16777216 + 2097152);
    __bf16* W2t = (__bf16*)(ws + 16777216 + 2097152 + 32768);
    __bf16* W3t = (__bf16*)(ws + 16777216 + 2097152 + 65536);

    hipLaunchKernelGGL(w23_kernel, dim3(16), dim3(256), 0, stream, W2, W3, W2t, W3t);
    hipLaunchKernelGGL(prep_kernel, dim3(768), dim3(256), 0, stream,
                       X, W1, W2t, b2, W3t, b3, Xb, W1t, Sv);
    hipLaunchKernelGGL(gemm_kernel, dim3((ROWS / 128) * (Dd / 128)), dim3(256), 0, stream,
                       Xb, W1t, Sv, b1, Y);
}

// Round 8
// 146.473 us; speedup vs baseline: 1.0048x; 1.0048x over previous
//
#include <hip/hip_runtime.h>
#include <hip/hip_bf16.h>
#include <math.h>

// y[b,l,d] = x[b,l,d] * softplus((x@W1+b1)[b,l,d]) * sum_n((x@W2+b2)*(x@W3+b3))[b,l,n]

namespace {

constexpr int Dd   = 1024;
constexpr int ROWS = 8192;

typedef __bf16 bf16x8 __attribute__((ext_vector_type(8)));
typedef float  floatx4 __attribute__((ext_vector_type(4)));

__device__ __forceinline__ float softplus_fast(float v) {
    float l = __logf(1.0f + __expf(v));
    return v > 15.0f ? v : l;
}
__device__ __forceinline__ float bf_lo(unsigned short u) {
    union { unsigned q; float f; } c; c.q = ((unsigned)u) << 16; return c.f;
}

// ---------------------------------------------------------------------------
// w23: grid 16 — W2,W3 [k][16] fp32 -> W2t,W3t [16][k] bf16.
// ---------------------------------------------------------------------------
__global__ __launch_bounds__(256) void w23_kernel(
    const float* __restrict__ W2, const float* __restrict__ W3,
    __bf16* __restrict__ W2t, __bf16* __restrict__ W3t)
{
    const int t  = threadIdx.x;
    const int n  = t >> 4;
    const int k0 = blockIdx.x * 64 + (t & 15) * 4;
    ushort4 a, b;
    union { __bf16 h; unsigned short u; } c;
    c.h = (__bf16)W2[(size_t)(k0 + 0) * 16 + n]; a.x = c.u;
    c.h = (__bf16)W2[(size_t)(k0 + 1) * 16 + n]; a.y = c.u;
    c.h = (__bf16)W2[(size_t)(k0 + 2) * 16 + n]; a.z = c.u;
    c.h = (__bf16)W2[(size_t)(k0 + 3) * 16 + n]; a.w = c.u;
    c.h = (__bf16)W3[(size_t)(k0 + 0) * 16 + n]; b.x = c.u;
    c.h = (__bf16)W3[(size_t)(k0 + 1) * 16 + n]; b.y = c.u;
    c.h = (__bf16)W3[(size_t)(k0 + 2) * 16 + n]; b.z = c.u;
    c.h = (__bf16)W3[(size_t)(k0 + 3) * 16 + n]; b.w = c.u;
    *(ushort4*)&W2t[(size_t)n * Dd + k0] = a;
    *(ushort4*)&W3t[(size_t)n * Dd + k0] = b;
}

// ---------------------------------------------------------------------------
// prep: blocks 0..511 — 16 rows each: x fp32 -> bf16 Xb (A-frag layout) and
//       s[row] via MFMA vs W2t/W3t b128 frags. 4 waves K-split 256.
//       blocks 512..767 — W1 [k][n] fp32 -> W1t [n][k] bf16 (64x64 tiles).
// ---------------------------------------------------------------------------
__global__ __launch_bounds__(256, 4) void prep_kernel(
    const float* __restrict__ X, const float* __restrict__ W1,
    const __bf16* __restrict__ W2t, const float* __restrict__ b2,
    const __bf16* __restrict__ W3t, const float* __restrict__ b3,
    __bf16* __restrict__ Xb, __bf16* __restrict__ W1t, float* __restrict__ Sv)
{
    const int t = threadIdx.x;

    if (blockIdx.x >= 512) {
        __shared__ __bf16 tile[64][66];
        const int bidx = blockIdx.x - 512;
        const int bi = bidx >> 4, bj = bidx & 15;
        const int c = t & 63, r4 = t >> 6;
        #pragma unroll
        for (int i = 0; i < 16; ++i) {
            const int r = i * 4 + r4;
            tile[r][c] = (__bf16)W1[(size_t)(bi * 64 + r) * Dd + bj * 64 + c];
        }
        __syncthreads();
        #pragma unroll
        for (int i = 0; i < 16; ++i) {
            const int r = i * 4 + r4;
            W1t[(size_t)(bj * 64 + r) * Dd + bi * 64 + c] = tile[c][r];
        }
        return;
    }

    __shared__ float red[4][2][16][16];   // [wave][B/C][row][n]
    const int w = t >> 6, lane = t & 63;
    const int l15 = lane & 15, quad = lane >> 4;
    const int row0 = blockIdx.x * 16;
    const int kw = w * 256;
    const size_t xoff = (size_t)(row0 + l15) * Dd;
    const size_t woff = (size_t)l15 * Dd;

    floatx4 acc0 = {0.f, 0.f, 0.f, 0.f}, acc1 = {0.f, 0.f, 0.f, 0.f};
    #pragma unroll
    for (int ks = 0; ks < 8; ++ks) {
        const int k0 = kw + ks * 32 + quad * 8;
        const float4 xa = *(const float4*)&X[xoff + k0];
        const float4 xb = *(const float4*)&X[xoff + k0 + 4];
        bf16x8 af;
        af[0] = (__bf16)xa.x; af[1] = (__bf16)xa.y;
        af[2] = (__bf16)xa.z; af[3] = (__bf16)xa.w;
        af[4] = (__bf16)xb.x; af[5] = (__bf16)xb.y;
        af[6] = (__bf16)xb.z; af[7] = (__bf16)xb.w;
        *(bf16x8*)&Xb[xoff + k0] = af;
        const bf16x8 w2f = *(const bf16x8*)&W2t[woff + k0];
        const bf16x8 w3f = *(const bf16x8*)&W3t[woff + k0];
        acc0 = __builtin_amdgcn_mfma_f32_16x16x32_bf16(af, w2f, acc0, 0, 0, 0);
        acc1 = __builtin_amdgcn_mfma_f32_16x16x32_bf16(af, w3f, acc1, 0, 0, 0);
    }
    #pragma unroll
    for (int r = 0; r < 4; ++r) {
        red[w][0][quad * 4 + r][l15] = acc0[r];
        red[w][1][quad * 4 + r][l15] = acc1[r];
    }
    __syncthreads();
    {
        const int r = t >> 4, n = t & 15;
        float B = b2[n], C = b3[n];
        #pragma unroll
        for (int ww = 0; ww < 4; ++ww) {
            B += red[ww][0][r][n];
            C += red[ww][1][r][n];
        }
        float p = B * C;
        p += __shfl_xor(p, 1); p += __shfl_xor(p, 2);
        p += __shfl_xor(p, 4); p += __shfl_xor(p, 8);
        if (n == 0) Sv[row0 + r] = p;
    }
}

// ---------------------------------------------------------------------------
// gemm: 128x128 tile, BK=32. 3-stage pipeline with ONE fused
// `s_waitcnt lgkmcnt(0); s_barrier` per K-tile. Transport is regular
// global_load_dwordx4 -> VGPR (depth-3 prefetch: load tile t+3, ds_write
// tile t+1, compute tile t) -> ds_write_b128. Regular loads allocate in
// L2/L3 (R3: 21 MB fetch) unlike global_load_lds DMA (R7: 74 MB fetch,
// HBM-bound). Hazards: buf[(t+1)%3] writer at iter t vs readers at t-2,
// separated by barrier t-1 whose lgkmcnt(0) drains reader ds_reads.
// XOR-slot swizzled LDS (conflict-free). Fused epilogue.
// ---------------------------------------------------------------------------
__global__ __launch_bounds__(256, 2) void gemm_kernel(
    const __bf16* __restrict__ Xb, const __bf16* __restrict__ W1t,
    const float* __restrict__ Sv, const float* __restrict__ b1,
    float* __restrict__ Y)
{
    // 3 tile buffers x (A 4096 + B 4096 bf16) = 48 KB
    __shared__ __attribute__((aligned(16))) __bf16 lds[3 * 8192];
    const int t = threadIdx.x, lane = t & 63;
    const int w = t >> 6, wm = w & 1, wn = w >> 1;
    const int l15 = lane & 15, quad = lane >> 4;
    const int cb = blockIdx.x & 7, rb = blockIdx.x >> 3;  // cb ~ XCD id
    const int row0 = rb * 128, col0 = cb * 128;

    floatx4 acc[4][4] = {};

    // staging map: slot u -> (rowL, chunk) with c4 = (u&7)^((u>>3)&7)
    const __bf16* gA[2]; const __bf16* gB[2];
    int dA[2], dB[2];
    #pragma unroll
    for (int r = 0; r < 2; ++r) {
        const int u = r * 256 + t;
        const int p = u >> 3, s = u & 7, c4 = s ^ (p & 7);
        const int rowL = 2 * p + (c4 >> 2), chk = c4 & 3;
        gA[r] = Xb  + (size_t)(row0 + rowL) * Dd + chk * 8;
        gB[r] = W1t + (size_t)(col0 + rowL) * Dd + chk * 8;
        dA[r] = u * 8;
        dB[r] = 4096 + u * 8;
    }

    bf16x8 vA[3][2], vB[3][2];

    auto gload = [&](int vb, int tt) {
        #pragma unroll
        for (int r = 0; r < 2; ++r) {
            vA[vb][r] = *(const bf16x8*)(gA[r] + tt * 32);
            vB[vb][r] = *(const bf16x8*)(gB[r] + tt * 32);
        }
    };
    auto dswrite = [&](int vb, int c) {
        const int base = c * 8192;
        #pragma unroll
        for (int r = 0; r < 2; ++r) {
            *(bf16x8*)&lds[base + dA[r]] = vA[vb][r];
            *(bf16x8*)&lds[base + dB[r]] = vB[vb][r];
        }
    };
    auto compute = [&](int c) {
        const int base = c * 8192;
        bf16x8 af[4], bfr[4];
        #pragma unroll
        for (int mt = 0; mt < 4; ++mt) {
            const int rl = wm * 64 + mt * 16 + l15;
            const int p = rl >> 1, c4 = ((rl & 1) << 2) | quad, s = c4 ^ (p & 7);
            af[mt] = *(const bf16x8*)&lds[base + p * 64 + s * 8];
        }
        #pragma unroll
        for (int nt = 0; nt < 4; ++nt) {
            const int nl = wn * 64 + nt * 16 + l15;
            const int p = nl >> 1, c4 = ((nl & 1) << 2) | quad, s = c4 ^ (p & 7);
            bfr[nt] = *(const bf16x8*)&lds[base + 4096 + p * 64 + s * 8];
        }
        #pragma unroll
        for (int mt = 0; mt < 4; ++mt)
            #pragma unroll
            for (int nt = 0; nt < 4; ++nt)
                acc[mt][nt] = __builtin_amdgcn_mfma_f32_16x16x32_bf16(
                    af[mt], bfr[nt], acc[mt][nt], 0, 0, 0);
    };

    gload(0, 0);
    gload(1, 1);
    gload(2, 2);
    dswrite(0, 0);
    #pragma unroll
    for (int tt = 0; tt < 32; ++tt) {
        // one barrier per tile: drains this wave's ds ops; all waves' writes
        // of buf[tt%3] (issued last iter) are visible after it.
        asm volatile("s_waitcnt lgkmcnt(0)\n\ts_barrier" ::: "memory");
        if (tt + 1 < 32) dswrite((tt + 1) % 3, (tt + 1) % 3);
        if (tt + 3 < 32) gload(tt % 3, tt + 3);
        compute(tt % 3);
    }

    // epilogue: C/D layout col = l15, row = quad*4 + rr
    float bias[4];
    #pragma unroll
    for (int nt = 0; nt < 4; ++nt) bias[nt] = b1[col0 + wn * 64 + nt * 16 + l15];

    #pragma unroll
    for (int mt = 0; mt < 4; ++mt) {
        #pragma unroll
        for (int rr = 0; rr < 4; ++rr) {
            const int row = row0 + wm * 64 + mt * 16 + quad * 4 + rr;
            const float sv = Sv[row];
            const unsigned short* xrow =
                (const unsigned short*)(Xb + (size_t)row * Dd + col0);
            float* yrow = Y + (size_t)row * Dd + col0;
            #pragma unroll
            for (int nt = 0; nt < 4; ++nt) {
                const int cl = wn * 64 + nt * 16 + l15;
                const float v  = acc[mt][nt][rr] + bias[nt];
                const float sp = softplus_fast(v);
                yrow[cl] = bf_lo(xrow[cl]) * sp * sv;
            }
        }
    }
}

} // namespace

extern "C" void kernel_launch(void* const* d_in, const int* in_sizes, int n_in,
                              void* d_out, int out_size, void* d_ws, size_t ws_size,
                              hipStream_t stream)
{
    const float* X  = (const float*)d_in[0];
    const float* W1 = (const float*)d_in[1];
    const float* b1 = (const float*)d_in[2];
    const float* W2 = (const float*)d_in[3];
    const float* b2 = (const float*)d_in[4];
    const float* W3 = (const float*)d_in[5];
    const float* b3 = (const float*)d_in[6];
    // d_in[7] = A is dead code in the reference.
    float* Y = (float*)d_out;

    // workspace: Xb 16MB | W1t 2MB | Sv 32KB | W2t 32KB | W3t 32KB
    char* ws = (char*)d_ws;
    __bf16* Xb  = (__bf16*)ws;
    __bf16* W1t = (__bf16*)(ws + 16777216);
    float*  Sv  = (float*) (ws + 16777216 + 2097152);
    __bf16* W2t = (__bf16*)(ws + 16777216 + 2097152 + 32768);
    __bf16* W3t = (__bf16*)(ws + 16777216 + 2097152 + 65536);

    hipLaunchKernelGGL(w23_kernel, dim3(16), dim3(256), 0, stream, W2, W3, W2t, W3t);
    hipLaunchKernelGGL(prep_kernel, dim3(768), dim3(256), 0, stream,
                       X, W1, W2t, b2, W3t, b3, Xb, W1t, Sv);
    hipLaunchKernelGGL(gemm_kernel, dim3((ROWS / 128) * (Dd / 128)), dim3(256), 0, stream,
                       Xb, W1t, Sv, b1, Y);
}